// Round 4
// baseline (1066.799 us; speedup 1.0000x reference)
//
#include <hip/hip_runtime.h>

#define BT (256*512)   // 131072 positions
#define HID 128
#define EMB 64

typedef unsigned short bf16_t;

__device__ inline float bf2f(bf16_t u) {
    union { unsigned int i; float f; } v; v.i = ((unsigned int)u) << 16; return v.f;
}
__device__ inline bf16_t f2bf(float f) {
    union { float f; unsigned int i; } v; v.f = f;
    unsigned int x = v.i;
    return (bf16_t)((x + 0x7fffu + ((x >> 16) & 1u)) >> 16);  // RNE
}
// tanh(x) = 1 - 2/(exp(2x)+1)  — stable at both infinities, ~1e-6 abs error
__device__ inline float fast_tanh(float x) {
    float e = __expf(2.f * x);
    return 1.f - __fdividef(2.f, e + 1.f);
}

// ---- explicit-register weight row; OPQ makes values opaque so the compiler
// ---- CANNOT sink the loads back into the loop (round-3 failure: VGPR=104).
#define OPQ(v) asm volatile("" : "+v"(v.x), "+v"(v.y), "+v"(v.z), "+v"(v.w))
#define W16DECL \
    float4 w0=wr[0],w1=wr[1],w2=wr[2],w3=wr[3],w4=wr[4],w5=wr[5],w6=wr[6],w7=wr[7], \
           w8=wr[8],w9=wr[9],w10=wr[10],w11=wr[11],w12=wr[12],w13=wr[13],w14=wr[14],w15=wr[15]; \
    OPQ(w0);OPQ(w1);OPQ(w2);OPQ(w3);OPQ(w4);OPQ(w5);OPQ(w6);OPQ(w7); \
    OPQ(w8);OPQ(w9);OPQ(w10);OPQ(w11);OPQ(w12);OPQ(w13);OPQ(w14);OPQ(w15);
#define W32DECL W16DECL \
    float4 w16=wr[16],w17=wr[17],w18=wr[18],w19=wr[19],w20=wr[20],w21=wr[21],w22=wr[22],w23=wr[23], \
           w24=wr[24],w25=wr[25],w26=wr[26],w27=wr[27],w28=wr[28],w29=wr[29],w30=wr[30],w31=wr[31]; \
    OPQ(w16);OPQ(w17);OPQ(w18);OPQ(w19);OPQ(w20);OPQ(w21);OPQ(w22);OPQ(w23); \
    OPQ(w24);OPQ(w25);OPQ(w26);OPQ(w27);OPQ(w28);OPQ(w29);OPQ(w30);OPQ(w31);
#define ACC4(n) { float4 hv = hp[n]; \
    a0 = fmaf(hv.x, w##n.x, a0); a1 = fmaf(hv.y, w##n.y, a1); \
    a2 = fmaf(hv.z, w##n.z, a2); a3 = fmaf(hv.w, w##n.w, a3); }
#define ACC16 ACC4(0)ACC4(1)ACC4(2)ACC4(3)ACC4(4)ACC4(5)ACC4(6)ACC4(7) \
              ACC4(8)ACC4(9)ACC4(10)ACC4(11)ACC4(12)ACC4(13)ACC4(14)ACC4(15)
#define ACC32 ACC16 \
              ACC4(16)ACC4(17)ACC4(18)ACC4(19)ACC4(20)ACC4(21)ACC4(22)ACC4(23) \
              ACC4(24)ACC4(25)ACC4(26)ACC4(27)ACC4(28)ACC4(29)ACC4(30)ACC4(31)

// ---------------- kernel 1: embedding gather + layer-1 input GEMM (+both biases)
__global__ __launch_bounds__(128, 4) void k_embed_pre1(
    const int* __restrict__ x, const float* __restrict__ emb,
    const float* __restrict__ Wih1, const float* __restrict__ bih1,
    const float* __restrict__ bhh1, float* __restrict__ pre1)
{
    __shared__ __align__(16) float se[8 * EMB];
    __shared__ int stok[8];
    const int base = blockIdx.x * 8;
    const int i = threadIdx.x;
    if (i < 8) stok[i] = x[base + i];
    __syncthreads();
    {   // gather 8 emb rows (16 float4 each) — one float4 per thread
        int p = i >> 4, c = i & 15;
        ((float4*)se)[i] = ((const float4*)(emb + (size_t)stok[p] * EMB))[c];
    }
    __syncthreads();
    const float4* wr = reinterpret_cast<const float4*>(Wih1 + i * EMB);
    W16DECL;
    const float bias = bih1[i] + bhh1[i];
    float* outp = pre1 + (size_t)base * HID + i;
#pragma unroll
    for (int p = 0; p < 8; ++p) {
        const float4* hp = reinterpret_cast<const float4*>(se + p * EMB);
        float a0 = 0, a1 = 0, a2 = 0, a3 = 0;
        ACC16;
        outp[p * HID] = bias + ((a0 + a1) + (a2 + a3));
    }
}

// ---------------- kernel 2: layer-1 recurrence. one block per batch row.
__global__ __launch_bounds__(128, 1) void k_rnn1(
    const float* __restrict__ pre1, const float* __restrict__ Whh1,
    bf16_t* __restrict__ out1)
{
    __shared__ __align__(16) float hb[2][HID];
    const int b = blockIdx.x;
    const int i = threadIdx.x;
    const float4* wr = reinterpret_cast<const float4*>(Whh1 + i * HID);
    W32DECL;
    hb[0][i] = 0.f;
    const float* p = pre1 + (size_t)b * 512 * HID + i;
    bf16_t*     o = out1 + (size_t)b * 512 * HID + i;
    float pcur = *p; p += HID;
    __syncthreads();
    for (int t = 0; t < 512; ++t) {
        float pnext = *p; p += HID;   // last iter overruns into out1 region (allocated, unused)
        const float4* hp = reinterpret_cast<const float4*>(hb[t & 1]);
        float a0 = pcur, a1 = 0, a2 = 0, a3 = 0;
        ACC32;
        float hn = fast_tanh((a0 + a1) + (a2 + a3));
        hb[(t + 1) & 1][i] = hn;      // other buffer: safe vs. ongoing reads
        *o = f2bf(hn); o += HID;
        __syncthreads();
        pcur = pnext;
    }
}

// ---------------- kernel 3: layer-2 input GEMM (+both biases), 16 positions/block
__global__ __launch_bounds__(128, 2) void k_pre2(
    const bf16_t* __restrict__ out1, const float* __restrict__ Wih2,
    const float* __restrict__ bih2, const float* __restrict__ bhh2,
    float* __restrict__ pre2)
{
    __shared__ __align__(16) float se[16 * HID];
    const int base = blockIdx.x * 16;
    const int i = threadIdx.x;
    // stage 16*128 bf16 = 2048 vals = 256 uint4; 2 uint4 per thread
    const uint4* src = reinterpret_cast<const uint4*>(out1 + (size_t)base * HID);
#pragma unroll
    for (int k = 0; k < 2; ++k) {
        int idx = i + k * 128;
        uint4 u = src[idx];
        int e = idx * 8;
        se[e+0] = bf2f((bf16_t)(u.x & 0xffff)); se[e+1] = bf2f((bf16_t)(u.x >> 16));
        se[e+2] = bf2f((bf16_t)(u.y & 0xffff)); se[e+3] = bf2f((bf16_t)(u.y >> 16));
        se[e+4] = bf2f((bf16_t)(u.z & 0xffff)); se[e+5] = bf2f((bf16_t)(u.z >> 16));
        se[e+6] = bf2f((bf16_t)(u.w & 0xffff)); se[e+7] = bf2f((bf16_t)(u.w >> 16));
    }
    __syncthreads();
    const float4* wr = reinterpret_cast<const float4*>(Wih2 + i * HID);
    W32DECL;
    const float bias = bih2[i] + bhh2[i];
    float* outp = pre2 + (size_t)base * HID + i;
#pragma unroll
    for (int p = 0; p < 16; ++p) {
        const float4* hp = reinterpret_cast<const float4*>(se + p * HID);
        float a0 = 0, a1 = 0, a2 = 0, a3 = 0;
        ACC32;
        outp[p * HID] = bias + ((a0 + a1) + (a2 + a3));
    }
}

// block-of-128 sum (2 waves)
__device__ inline float bsum128(float v, volatile float* sc, int tid) {
#pragma unroll
    for (int off = 32; off > 0; off >>= 1) v += __shfl_down(v, off, 64);
    __syncthreads();
    if ((tid & 63) == 0) sc[tid >> 6] = v;
    __syncthreads();
    return sc[0] + sc[1];
}

// ---------------- kernel 4: layer-2 recurrence + LN -> proj+tanh -> LN epilogue
__global__ __launch_bounds__(128, 1) void k_rnn2_out(
    const float* __restrict__ pre2, const float* __restrict__ Whh2,
    const float* __restrict__ ln_g, const float* __restrict__ ln_b,
    const float* __restrict__ projW, const float* __restrict__ proj_b,
    const float* __restrict__ on_g, const float* __restrict__ on_b,
    float* __restrict__ out)
{
    __shared__ __align__(16) float hb[2][HID];
    __shared__ float sc[2];
    const int b = blockIdx.x;
    const int i = threadIdx.x;
    {
        const float4* wr = reinterpret_cast<const float4*>(Whh2 + i * HID);
        W32DECL;
        hb[0][i] = 0.f;
        const float* p = pre2 + (size_t)b * 512 * HID + i;
        float pcur = *p; p += HID;
        __syncthreads();
        float hn = 0.f;
        for (int t = 0; t < 512; ++t) {
            float pnext = *p; p += HID;   // last iter overruns into out1 region (allocated)
            const float4* hp = reinterpret_cast<const float4*>(hb[t & 1]);
            float a0 = pcur, a1 = 0, a2 = 0, a3 = 0;
            ACC32;
            hn = fast_tanh((a0 + a1) + (a2 + a3));
            hb[(t + 1) & 1][i] = hn;
            __syncthreads();
            pcur = pnext;
        }
        // ---- layernorm 1
        float s1 = bsum128(hn, sc, i);
        float s2 = bsum128(hn * hn, sc, i);
        float mu = s1 * (1.f / 128.f);
        float var = s2 * (1.f / 128.f) - mu * mu;
        float rep = (hn - mu) * rsqrtf(var + 1e-5f) * ln_g[i] + ln_b[i];
        __syncthreads();
        hb[0][i] = rep;
        __syncthreads();
    }
    // ---- proj + tanh (precise tanhf once — off the critical path)
    float a0 = proj_b[i], a1 = 0, a2 = 0, a3 = 0;
    const float4* hp = reinterpret_cast<const float4*>(hb[0]);
    const float4* pr = reinterpret_cast<const float4*>(projW + i * HID);
#pragma unroll
    for (int c = 0; c < HID / 4; ++c) {
        float4 u = pr[c];
        float4 hv = hp[c];
        a0 = fmaf(hv.x, u.x, a0); a1 = fmaf(hv.y, u.y, a1);
        a2 = fmaf(hv.z, u.z, a2); a3 = fmaf(hv.w, u.w, a3);
    }
    float pv = tanhf((a0 + a1) + (a2 + a3));
    // ---- layernorm 2
    float t1 = bsum128(pv, sc, i);
    float t2 = bsum128(pv * pv, sc, i);
    float mu2 = t1 * (1.f / 128.f);
    float var2 = t2 * (1.f / 128.f) - mu2 * mu2;
    out[(size_t)b * HID + i] = (pv - mu2) * rsqrtf(var2 + 1e-5f) * on_g[i] + on_b[i];
}

extern "C" void kernel_launch(void* const* d_in, const int* in_sizes, int n_in,
                              void* d_out, int out_size, void* d_ws, size_t ws_size,
                              hipStream_t stream)
{
    const int*   x     = (const int*)  d_in[0];
    const float* emb   = (const float*)d_in[1];
    const float* Wih1  = (const float*)d_in[2];
    const float* bih1  = (const float*)d_in[3];
    const float* Whh1  = (const float*)d_in[4];
    const float* bhh1  = (const float*)d_in[5];
    const float* Wih2  = (const float*)d_in[6];
    const float* bih2  = (const float*)d_in[7];
    const float* Whh2  = (const float*)d_in[8];
    const float* bhh2  = (const float*)d_in[9];
    const float* ln_g  = (const float*)d_in[10];
    const float* ln_b  = (const float*)d_in[11];
    const float* projW = (const float*)d_in[12];
    const float* projb = (const float*)d_in[13];
    const float* on_g  = (const float*)d_in[14];
    const float* on_b  = (const float*)d_in[15];

    char* ws = (char*)d_ws;
    float*  pre  = (float*)ws;                               // 64 MiB fp32, reused by both layers
    bf16_t* out1 = (bf16_t*)(ws + (size_t)BT * HID * 4);     // 32 MiB bf16

    k_embed_pre1<<<BT / 8, 128, 0, stream>>>(x, emb, Wih1, bih1, bhh1, pre);
    k_rnn1<<<256, 128, 0, stream>>>(pre, Whh1, out1);
    k_pre2<<<BT / 16, 128, 0, stream>>>(out1, Wih2, bih2, bhh2, pre);
    k_rnn2_out<<<256, 128, 0, stream>>>(pre, Whh2, ln_g, ln_b, projW, projb,
                                        on_g, on_b, (float*)d_out);
}

// Round 5
// 922.176 us; speedup vs baseline: 1.1568x; 1.1568x over previous
//
#include <hip/hip_runtime.h>

#define BT (256*512)   // 131072 positions
#define HID 128
#define EMB 64

typedef unsigned short bf16_t;

__device__ inline float bf2f(bf16_t u) {
    union { unsigned int i; float f; } v; v.i = ((unsigned int)u) << 16; return v.f;
}
__device__ inline bf16_t f2bf(float f) {
    union { float f; unsigned int i; } v; v.f = f;
    unsigned int x = v.i;
    return (bf16_t)((x + 0x7fffu + ((x >> 16) & 1u)) >> 16);  // RNE
}
// tanh(x) = 1 - 2/(exp(2x)+1)  — stable at both infinities, ~1e-6 abs error
__device__ inline float fast_tanh(float x) {
    float e = __expf(2.f * x);
    return 1.f - __fdividef(2.f, e + 1.f);
}

// pin a float4 in VGPRs (compiler cannot rematerialize past this)
#define OPQ(v) asm volatile("" : "+v"(v.x), "+v"(v.y), "+v"(v.z), "+v"(v.w))

#define W16LOAD \
    float4 w0=wr[0],w1=wr[1],w2=wr[2],w3=wr[3],w4=wr[4],w5=wr[5],w6=wr[6],w7=wr[7], \
           w8=wr[8],w9=wr[9],w10=wr[10],w11=wr[11],w12=wr[12],w13=wr[13],w14=wr[14],w15=wr[15];
#define W16PIN \
    OPQ(w0);OPQ(w1);OPQ(w2);OPQ(w3);OPQ(w4);OPQ(w5);OPQ(w6);OPQ(w7); \
    OPQ(w8);OPQ(w9);OPQ(w10);OPQ(w11);OPQ(w12);OPQ(w13);OPQ(w14);OPQ(w15);
#define W32LOAD W16LOAD \
    float4 w16=wr[16],w17=wr[17],w18=wr[18],w19=wr[19],w20=wr[20],w21=wr[21],w22=wr[22],w23=wr[23], \
           w24=wr[24],w25=wr[25],w26=wr[26],w27=wr[27],w28=wr[28],w29=wr[29],w30=wr[30],w31=wr[31];
#define ACC4(n) { float4 hv = hp[n]; \
    a0 = fmaf(hv.x, w##n.x, a0); a1 = fmaf(hv.y, w##n.y, a1); \
    a2 = fmaf(hv.z, w##n.z, a2); a3 = fmaf(hv.w, w##n.w, a3); }
#define ACC16 ACC4(0)ACC4(1)ACC4(2)ACC4(3)ACC4(4)ACC4(5)ACC4(6)ACC4(7) \
              ACC4(8)ACC4(9)ACC4(10)ACC4(11)ACC4(12)ACC4(13)ACC4(14)ACC4(15)
#define ACC32 ACC16 \
              ACC4(16)ACC4(17)ACC4(18)ACC4(19)ACC4(20)ACC4(21)ACC4(22)ACC4(23) \
              ACC4(24)ACC4(25)ACC4(26)ACC4(27)ACC4(28)ACC4(29)ACC4(30)ACC4(31)

// ---------------- kernel 1: embedding gather + layer-1 input GEMM (+both biases)
__global__ __launch_bounds__(128, 4) void k_embed_pre1(
    const int* __restrict__ x, const float* __restrict__ emb,
    const float* __restrict__ Wih1, const float* __restrict__ bih1,
    const float* __restrict__ bhh1, float* __restrict__ pre1)
{
    __shared__ __align__(16) float se[8 * EMB];
    __shared__ int stok[8];
    const int base = blockIdx.x * 8;
    const int i = threadIdx.x;
    if (i < 8) stok[i] = x[base + i];
    __syncthreads();
    {   // gather 8 emb rows (16 float4 each) — one float4 per thread
        int p = i >> 4, c = i & 15;
        ((float4*)se)[i] = ((const float4*)(emb + (size_t)stok[p] * EMB))[c];
    }
    __syncthreads();
    const float4* wr = reinterpret_cast<const float4*>(Wih1 + i * EMB);
    W16LOAD;
    const float bias = bih1[i] + bhh1[i];
    float* outp = pre1 + (size_t)base * HID + i;
#pragma unroll
    for (int p = 0; p < 8; ++p) {
        const float4* hp = reinterpret_cast<const float4*>(se + p * EMB);
        float a0 = 0, a1 = 0, a2 = 0, a3 = 0;
        ACC16;
        outp[p * HID] = bias + ((a0 + a1) + (a2 + a3));
    }
}

// ---------------- kernel 2: layer-1 recurrence. one block per batch row,
// 256 threads: thread (i = tid&127, half = tid>>7) owns Whh[i][64*half..+64)
// in 16 pinned float4 (64 VGPRs — under the compiler's ~104-reg comfort zone).
__global__ __launch_bounds__(256, 1) void k_rnn1(
    const float* __restrict__ pre1, const float* __restrict__ Whh1,
    bf16_t* __restrict__ out1)
{
    __shared__ __align__(16) float hb[2][HID];   // double-buffered hidden state
    __shared__ __align__(16) float sp[2][HID];   // K-split partial sums
    const int b    = blockIdx.x;
    const int tid  = threadIdx.x;
    const int i    = tid & 127;
    const int half = tid >> 7;
    const float4* wr = reinterpret_cast<const float4*>(Whh1 + i * HID + half * 64);
    W16LOAD; W16PIN;
    if (tid < 128) hb[0][i] = 0.f;
    const float* p = pre1 + (size_t)b * 512 * HID + i;
    bf16_t*      o = out1 + (size_t)b * 512 * HID + i;
    float pcur = *p; p += HID;
    __syncthreads();
    for (int t = 0; t < 512; ++t) {
        float pnext = *p; p += HID;   // last iter overruns into out1 region (allocated)
        const float4* hp = reinterpret_cast<const float4*>(hb[t & 1] + half * 64);
        float a0 = 0, a1 = 0, a2 = 0, a3 = 0;
        ACC16;
        sp[half][i] = (a0 + a1) + (a2 + a3);
        __syncthreads();
        if (tid < 128) {   // wave-uniform branch (waves 0,1)
            float hn = fast_tanh(pcur + sp[0][i] + sp[1][i]);
            hb[(t + 1) & 1][i] = hn;
            *o = f2bf(hn);
        }
        o += HID;
        __syncthreads();
        pcur = pnext;
    }
}

// ---------------- kernel 3: layer-2 input GEMM (+both biases), 16 positions/block
__global__ __launch_bounds__(128, 2) void k_pre2(
    const bf16_t* __restrict__ out1, const float* __restrict__ Wih2,
    const float* __restrict__ bih2, const float* __restrict__ bhh2,
    float* __restrict__ pre2)
{
    __shared__ __align__(16) float se[16 * HID];
    const int base = blockIdx.x * 16;
    const int i = threadIdx.x;
    const uint4* src = reinterpret_cast<const uint4*>(out1 + (size_t)base * HID);
#pragma unroll
    for (int k = 0; k < 2; ++k) {
        int idx = i + k * 128;
        uint4 u = src[idx];
        int e = idx * 8;
        se[e+0] = bf2f((bf16_t)(u.x & 0xffff)); se[e+1] = bf2f((bf16_t)(u.x >> 16));
        se[e+2] = bf2f((bf16_t)(u.y & 0xffff)); se[e+3] = bf2f((bf16_t)(u.y >> 16));
        se[e+4] = bf2f((bf16_t)(u.z & 0xffff)); se[e+5] = bf2f((bf16_t)(u.z >> 16));
        se[e+6] = bf2f((bf16_t)(u.w & 0xffff)); se[e+7] = bf2f((bf16_t)(u.w >> 16));
    }
    __syncthreads();
    const float4* wr = reinterpret_cast<const float4*>(Wih2 + i * HID);
    W32LOAD;
    const float bias = bih2[i] + bhh2[i];
    float* outp = pre2 + (size_t)base * HID + i;
#pragma unroll
    for (int p = 0; p < 16; ++p) {
        const float4* hp = reinterpret_cast<const float4*>(se + p * HID);
        float a0 = 0, a1 = 0, a2 = 0, a3 = 0;
        ACC32;
        outp[p * HID] = bias + ((a0 + a1) + (a2 + a3));
    }
}

// block-wide sum over the 128 values held by tid<128 (all 256 threads call;
// half-1 threads must pass v=0). Unconditional barriers.
__device__ inline float bsum_all(float v, volatile float* sc, int tid) {
#pragma unroll
    for (int off = 32; off > 0; off >>= 1) v += __shfl_down(v, off, 64);
    __syncthreads();
    if (tid < 128 && (tid & 63) == 0) sc[tid >> 6] = v;
    __syncthreads();
    return sc[0] + sc[1];
}

// ---------------- kernel 4: layer-2 recurrence + LN -> proj+tanh -> LN epilogue
__global__ __launch_bounds__(256, 1) void k_rnn2_out(
    const float* __restrict__ pre2, const float* __restrict__ Whh2,
    const float* __restrict__ ln_g, const float* __restrict__ ln_b,
    const float* __restrict__ projW, const float* __restrict__ proj_b,
    const float* __restrict__ on_g, const float* __restrict__ on_b,
    float* __restrict__ out)
{
    __shared__ __align__(16) float hb[2][HID];
    __shared__ __align__(16) float sp[2][HID];
    __shared__ float sc[2];
    const int b    = blockIdx.x;
    const int tid  = threadIdx.x;
    const int i    = tid & 127;
    const int half = tid >> 7;
    const float4* wr = reinterpret_cast<const float4*>(Whh2 + i * HID + half * 64);
    W16LOAD; W16PIN;
    if (tid < 128) hb[0][i] = 0.f;
    const float* p = pre2 + (size_t)b * 512 * HID + i;
    float pcur = *p; p += HID;
    __syncthreads();
    float hn = 0.f;                 // final h, valid for tid<128
    for (int t = 0; t < 512; ++t) {
        float pnext = *p; p += HID; // last iter overruns into out1 region (allocated)
        const float4* hp = reinterpret_cast<const float4*>(hb[t & 1] + half * 64);
        float a0 = 0, a1 = 0, a2 = 0, a3 = 0;
        ACC16;
        sp[half][i] = (a0 + a1) + (a2 + a3);
        __syncthreads();
        if (tid < 128) {
            hn = fast_tanh(pcur + sp[0][i] + sp[1][i]);
            hb[(t + 1) & 1][i] = hn;
        }
        __syncthreads();
        pcur = pnext;
    }
    // ---- layernorm 1 (values valid for tid<128; barriers executed by all)
    float s1 = bsum_all(tid < 128 ? hn : 0.f, sc, tid);
    float s2 = bsum_all(tid < 128 ? hn * hn : 0.f, sc, tid);
    float mu = s1 * (1.f / 128.f);
    float var = s2 * (1.f / 128.f) - mu * mu;
    __syncthreads();
    if (tid < 128) hb[0][i] = (hn - mu) * rsqrtf(var + 1e-5f) * ln_g[i] + ln_b[i];
    __syncthreads();
    // ---- proj + tanh (one-time; first 128 threads)
    float pv = 0.f;
    if (tid < 128) {
        float a0 = proj_b[i], a1 = 0, a2 = 0, a3 = 0;
        const float4* hp = reinterpret_cast<const float4*>(hb[0]);
        const float4* pr = reinterpret_cast<const float4*>(projW + i * HID);
#pragma unroll
        for (int c = 0; c < HID / 4; ++c) {
            float4 u = pr[c];
            float4 hv = hp[c];
            a0 = fmaf(hv.x, u.x, a0); a1 = fmaf(hv.y, u.y, a1);
            a2 = fmaf(hv.z, u.z, a2); a3 = fmaf(hv.w, u.w, a3);
        }
        pv = tanhf((a0 + a1) + (a2 + a3));
    }
    // ---- layernorm 2
    float t1 = bsum_all(pv, sc, tid);
    float t2 = bsum_all(pv * pv, sc, tid);
    float mu2 = t1 * (1.f / 128.f);
    float var2 = t2 * (1.f / 128.f) - mu2 * mu2;
    if (tid < 128)
        out[(size_t)b * HID + i] = (pv - mu2) * rsqrtf(var2 + 1e-5f) * on_g[i] + on_b[i];
}

extern "C" void kernel_launch(void* const* d_in, const int* in_sizes, int n_in,
                              void* d_out, int out_size, void* d_ws, size_t ws_size,
                              hipStream_t stream)
{
    const int*   x     = (const int*)  d_in[0];
    const float* emb   = (const float*)d_in[1];
    const float* Wih1  = (const float*)d_in[2];
    const float* bih1  = (const float*)d_in[3];
    const float* Whh1  = (const float*)d_in[4];
    const float* bhh1  = (const float*)d_in[5];
    const float* Wih2  = (const float*)d_in[6];
    const float* bih2  = (const float*)d_in[7];
    const float* Whh2  = (const float*)d_in[8];
    const float* bhh2  = (const float*)d_in[9];
    const float* ln_g  = (const float*)d_in[10];
    const float* ln_b  = (const float*)d_in[11];
    const float* projW = (const float*)d_in[12];
    const float* projb = (const float*)d_in[13];
    const float* on_g  = (const float*)d_in[14];
    const float* on_b  = (const float*)d_in[15];

    char* ws = (char*)d_ws;
    float*  pre  = (float*)ws;                               // 64 MiB fp32, reused by both layers
    bf16_t* out1 = (bf16_t*)(ws + (size_t)BT * HID * 4);     // 32 MiB bf16

    k_embed_pre1<<<BT / 8, 128, 0, stream>>>(x, emb, Wih1, bih1, bhh1, pre);
    k_rnn1<<<256, 256, 0, stream>>>(pre, Whh1, out1);
    k_pre2<<<BT / 16, 128, 0, stream>>>(out1, Wih2, bih2, bhh2, pre);
    k_rnn2_out<<<256, 256, 0, stream>>>(pre, Whh2, ln_g, ln_b, projW, projb,
                                        on_g, on_b, (float*)d_out);
}

// Round 6
// 837.439 us; speedup vs baseline: 1.2739x; 1.1012x over previous
//
#include <hip/hip_runtime.h>

#define BT (256*512)   // 131072 positions
#define HID 128
#define EMB 64

typedef unsigned short bf16_t;

__device__ inline float bf2f(bf16_t u) {
    union { unsigned int i; float f; } v; v.i = ((unsigned int)u) << 16; return v.f;
}
__device__ inline bf16_t f2bf(float f) {
    union { float f; unsigned int i; } v; v.f = f;
    unsigned int x = v.i;
    return (bf16_t)((x + 0x7fffu + ((x >> 16) & 1u)) >> 16);  // RNE
}
// tanh(x) = 1 - 2/(exp(2x)+1)  — stable at both infinities, ~1e-6 abs error
__device__ inline float fast_tanh(float x) {
    float e = __expf(2.f * x);
    return 1.f - __fdividef(2.f, e + 1.f);
}

// pin a float4 in VGPRs (compiler cannot rematerialize past this)
#define OPQ(v) asm volatile("" : "+v"(v.x), "+v"(v.y), "+v"(v.z), "+v"(v.w))

#define W16LOAD \
    float4 w0=wr[0],w1=wr[1],w2=wr[2],w3=wr[3],w4=wr[4],w5=wr[5],w6=wr[6],w7=wr[7], \
           w8=wr[8],w9=wr[9],w10=wr[10],w11=wr[11],w12=wr[12],w13=wr[13],w14=wr[14],w15=wr[15];
#define W16PIN \
    OPQ(w0);OPQ(w1);OPQ(w2);OPQ(w3);OPQ(w4);OPQ(w5);OPQ(w6);OPQ(w7); \
    OPQ(w8);OPQ(w9);OPQ(w10);OPQ(w11);OPQ(w12);OPQ(w13);OPQ(w14);OPQ(w15);
#define W32LOAD W16LOAD \
    float4 w16=wr[16],w17=wr[17],w18=wr[18],w19=wr[19],w20=wr[20],w21=wr[21],w22=wr[22],w23=wr[23], \
           w24=wr[24],w25=wr[25],w26=wr[26],w27=wr[27],w28=wr[28],w29=wr[29],w30=wr[30],w31=wr[31];
#define W32PIN W16PIN \
    OPQ(w16);OPQ(w17);OPQ(w18);OPQ(w19);OPQ(w20);OPQ(w21);OPQ(w22);OPQ(w23); \
    OPQ(w24);OPQ(w25);OPQ(w26);OPQ(w27);OPQ(w28);OPQ(w29);OPQ(w30);OPQ(w31);
#define ACC4(n) { float4 hv = hp[n]; \
    a0 = fmaf(hv.x, w##n.x, a0); a1 = fmaf(hv.y, w##n.y, a1); \
    a2 = fmaf(hv.z, w##n.z, a2); a3 = fmaf(hv.w, w##n.w, a3); }
#define ACC16 ACC4(0)ACC4(1)ACC4(2)ACC4(3)ACC4(4)ACC4(5)ACC4(6)ACC4(7) \
              ACC4(8)ACC4(9)ACC4(10)ACC4(11)ACC4(12)ACC4(13)ACC4(14)ACC4(15)
#define ACC32 ACC16 \
              ACC4(16)ACC4(17)ACC4(18)ACC4(19)ACC4(20)ACC4(21)ACC4(22)ACC4(23) \
              ACC4(24)ACC4(25)ACC4(26)ACC4(27)ACC4(28)ACC4(29)ACC4(30)ACC4(31)

// ---------------- kernel 1: embedding gather + layer-1 input GEMM (+both biases)
__global__ __launch_bounds__(128)
__attribute__((amdgpu_waves_per_eu(1, 4)))
void k_embed_pre1(
    const int* __restrict__ x, const float* __restrict__ emb,
    const float* __restrict__ Wih1, const float* __restrict__ bih1,
    const float* __restrict__ bhh1, float* __restrict__ pre1)
{
    __shared__ __align__(16) float se[8 * EMB];
    __shared__ int stok[8];
    const int base = blockIdx.x * 8;
    const int i = threadIdx.x;
    if (i < 8) stok[i] = x[base + i];
    __syncthreads();
    {   // gather 8 emb rows (16 float4 each) — one float4 per thread
        int p = i >> 4, c = i & 15;
        ((float4*)se)[i] = ((const float4*)(emb + (size_t)stok[p] * EMB))[c];
    }
    __syncthreads();
    const float4* wr = reinterpret_cast<const float4*>(Wih1 + i * EMB);
    W16LOAD; W16PIN;
    const float bias = bih1[i] + bhh1[i];
    float* outp = pre1 + (size_t)base * HID + i;
#pragma unroll
    for (int p = 0; p < 8; ++p) {
        const float4* hp = reinterpret_cast<const float4*>(se + p * EMB);
        float a0 = 0, a1 = 0, a2 = 0, a3 = 0;
        ACC16;
        outp[p * HID] = bias + ((a0 + a1) + (a2 + a3));
    }
}

// ---------------- kernel 2: layer-1 recurrence. one block per batch row,
// 256 threads: thread (i = tid&127, half = tid>>7) owns Whh[i][64*half..+64)
// in 16 pinned float4. waves_per_eu(1,1): allocator budget 512 VGPR, no
// occupancy squeeze (rounds 3-5 failure: allocator spilled/sank at 60-104).
__global__ __launch_bounds__(256)
__attribute__((amdgpu_waves_per_eu(1, 1)))
void k_rnn1(
    const float* __restrict__ pre1, const float* __restrict__ Whh1,
    bf16_t* __restrict__ out1)
{
    __shared__ __align__(16) float hb[2][HID];   // double-buffered hidden state
    __shared__ __align__(16) float sp[2][HID];   // K-split partial sums
    const int b    = blockIdx.x;
    const int tid  = threadIdx.x;
    const int i    = tid & 127;
    const int half = tid >> 7;
    const float4* wr = reinterpret_cast<const float4*>(Whh1 + i * HID + half * 64);
    W16LOAD; W16PIN;
    if (tid < 128) hb[0][i] = 0.f;
    const float* p = pre1 + (size_t)b * 512 * HID + i;
    bf16_t*      o = out1 + (size_t)b * 512 * HID + i;
    float pcur = *p; p += HID;
    __syncthreads();
    for (int t = 0; t < 512; ++t) {
        float pnext = *p; p += HID;   // last iter overruns into out1 region (allocated)
        const float4* hp = reinterpret_cast<const float4*>(hb[t & 1] + half * 64);
        float a0 = 0, a1 = 0, a2 = 0, a3 = 0;
        ACC16;
        sp[half][i] = (a0 + a1) + (a2 + a3);
        __syncthreads();
        if (tid < 128) {   // wave-uniform branch (waves 0,1)
            float hn = fast_tanh(pcur + sp[0][i] + sp[1][i]);
            hb[(t + 1) & 1][i] = hn;
            *o = f2bf(hn);
        }
        o += HID;
        __syncthreads();
        pcur = pnext;
    }
}

// ---------------- kernel 3: layer-2 input GEMM (+both biases), 16 positions/block
__global__ __launch_bounds__(128)
__attribute__((amdgpu_waves_per_eu(1, 2)))
void k_pre2(
    const bf16_t* __restrict__ out1, const float* __restrict__ Wih2,
    const float* __restrict__ bih2, const float* __restrict__ bhh2,
    float* __restrict__ pre2)
{
    __shared__ __align__(16) float se[16 * HID];
    const int base = blockIdx.x * 16;
    const int i = threadIdx.x;
    const uint4* src = reinterpret_cast<const uint4*>(out1 + (size_t)base * HID);
#pragma unroll
    for (int k = 0; k < 2; ++k) {
        int idx = i + k * 128;
        uint4 u = src[idx];
        int e = idx * 8;
        se[e+0] = bf2f((bf16_t)(u.x & 0xffff)); se[e+1] = bf2f((bf16_t)(u.x >> 16));
        se[e+2] = bf2f((bf16_t)(u.y & 0xffff)); se[e+3] = bf2f((bf16_t)(u.y >> 16));
        se[e+4] = bf2f((bf16_t)(u.z & 0xffff)); se[e+5] = bf2f((bf16_t)(u.z >> 16));
        se[e+6] = bf2f((bf16_t)(u.w & 0xffff)); se[e+7] = bf2f((bf16_t)(u.w >> 16));
    }
    __syncthreads();
    const float4* wr = reinterpret_cast<const float4*>(Wih2 + i * HID);
    W32LOAD; W32PIN;
    const float bias = bih2[i] + bhh2[i];
    float* outp = pre2 + (size_t)base * HID + i;
#pragma unroll
    for (int p = 0; p < 16; ++p) {
        const float4* hp = reinterpret_cast<const float4*>(se + p * HID);
        float a0 = 0, a1 = 0, a2 = 0, a3 = 0;
        ACC32;
        outp[p * HID] = bias + ((a0 + a1) + (a2 + a3));
    }
}

// block-wide sum over the 128 values held by tid<128 (all 256 threads call;
// half-1 threads must pass v=0). Unconditional barriers.
__device__ inline float bsum_all(float v, volatile float* sc, int tid) {
#pragma unroll
    for (int off = 32; off > 0; off >>= 1) v += __shfl_down(v, off, 64);
    __syncthreads();
    if (tid < 128 && (tid & 63) == 0) sc[tid >> 6] = v;
    __syncthreads();
    return sc[0] + sc[1];
}

// ---------------- kernel 4: layer-2 recurrence + LN -> proj+tanh -> LN epilogue
__global__ __launch_bounds__(256)
__attribute__((amdgpu_waves_per_eu(1, 1)))
void k_rnn2_out(
    const float* __restrict__ pre2, const float* __restrict__ Whh2,
    const float* __restrict__ ln_g, const float* __restrict__ ln_b,
    const float* __restrict__ projW, const float* __restrict__ proj_b,
    const float* __restrict__ on_g, const float* __restrict__ on_b,
    float* __restrict__ out)
{
    __shared__ __align__(16) float hb[2][HID];
    __shared__ __align__(16) float sp[2][HID];
    __shared__ float sc[2];
    const int b    = blockIdx.x;
    const int tid  = threadIdx.x;
    const int i    = tid & 127;
    const int half = tid >> 7;
    const float4* wr = reinterpret_cast<const float4*>(Whh2 + i * HID + half * 64);
    W16LOAD; W16PIN;
    if (tid < 128) hb[0][i] = 0.f;
    const float* p = pre2 + (size_t)b * 512 * HID + i;
    float pcur = *p; p += HID;
    __syncthreads();
    float hn = 0.f;                 // final h, valid for tid<128
    for (int t = 0; t < 512; ++t) {
        float pnext = *p; p += HID; // last iter overruns into out1 region (allocated)
        const float4* hp = reinterpret_cast<const float4*>(hb[t & 1] + half * 64);
        float a0 = 0, a1 = 0, a2 = 0, a3 = 0;
        ACC16;
        sp[half][i] = (a0 + a1) + (a2 + a3);
        __syncthreads();
        if (tid < 128) {
            hn = fast_tanh(pcur + sp[0][i] + sp[1][i]);
            hb[(t + 1) & 1][i] = hn;
        }
        __syncthreads();
        pcur = pnext;
    }
    // ---- layernorm 1 (values valid for tid<128; barriers executed by all)
    float s1 = bsum_all(tid < 128 ? hn : 0.f, sc, tid);
    float s2 = bsum_all(tid < 128 ? hn * hn : 0.f, sc, tid);
    float mu = s1 * (1.f / 128.f);
    float var = s2 * (1.f / 128.f) - mu * mu;
    __syncthreads();
    if (tid < 128) hb[0][i] = (hn - mu) * rsqrtf(var + 1e-5f) * ln_g[i] + ln_b[i];
    __syncthreads();
    // ---- proj + tanh (one-time; first 128 threads)
    float pv = 0.f;
    if (tid < 128) {
        float a0 = proj_b[i], a1 = 0, a2 = 0, a3 = 0;
        const float4* hp = reinterpret_cast<const float4*>(hb[0]);
        const float4* pr = reinterpret_cast<const float4*>(projW + i * HID);
#pragma unroll
        for (int c = 0; c < HID / 4; ++c) {
            float4 u = pr[c];
            float4 hv = hp[c];
            a0 = fmaf(hv.x, u.x, a0); a1 = fmaf(hv.y, u.y, a1);
            a2 = fmaf(hv.z, u.z, a2); a3 = fmaf(hv.w, u.w, a3);
        }
        pv = tanhf((a0 + a1) + (a2 + a3));
    }
    // ---- layernorm 2
    float t1 = bsum_all(pv, sc, tid);
    float t2 = bsum_all(pv * pv, sc, tid);
    float mu2 = t1 * (1.f / 128.f);
    float var2 = t2 * (1.f / 128.f) - mu2 * mu2;
    if (tid < 128)
        out[(size_t)b * HID + i] = (pv - mu2) * rsqrtf(var2 + 1e-5f) * on_g[i] + on_b[i];
}

extern "C" void kernel_launch(void* const* d_in, const int* in_sizes, int n_in,
                              void* d_out, int out_size, void* d_ws, size_t ws_size,
                              hipStream_t stream)
{
    const int*   x     = (const int*)  d_in[0];
    const float* emb   = (const float*)d_in[1];
    const float* Wih1  = (const float*)d_in[2];
    const float* bih1  = (const float*)d_in[3];
    const float* Whh1  = (const float*)d_in[4];
    const float* bhh1  = (const float*)d_in[5];
    const float* Wih2  = (const float*)d_in[6];
    const float* bih2  = (const float*)d_in[7];
    const float* Whh2  = (const float*)d_in[8];
    const float* bhh2  = (const float*)d_in[9];
    const float* ln_g  = (const float*)d_in[10];
    const float* ln_b  = (const float*)d_in[11];
    const float* projW = (const float*)d_in[12];
    const float* projb = (const float*)d_in[13];
    const float* on_g  = (const float*)d_in[14];
    const float* on_b  = (const float*)d_in[15];

    char* ws = (char*)d_ws;
    float*  pre  = (float*)ws;                               // 64 MiB fp32, reused by both layers
    bf16_t* out1 = (bf16_t*)(ws + (size_t)BT * HID * 4);     // 32 MiB bf16

    k_embed_pre1<<<BT / 8, 128, 0, stream>>>(x, emb, Wih1, bih1, bhh1, pre);
    k_rnn1<<<256, 256, 0, stream>>>(pre, Whh1, out1);
    k_pre2<<<BT / 16, 128, 0, stream>>>(out1, Wih2, bih2, bhh2, pre);
    k_rnn2_out<<<256, 256, 0, stream>>>(pre, Whh2, ln_g, ln_b, projW, projb,
                                        on_g, on_b, (float*)d_out);
}

// Round 7
// 811.140 us; speedup vs baseline: 1.3152x; 1.0324x over previous
//
#include <hip/hip_runtime.h>

#define BT (256*512)   // 131072 positions
#define HID 128
#define EMB 64
#define CH 32          // scan chunk: steps staged per LDS refill

typedef unsigned short bf16_t;

__device__ inline float bf2f(bf16_t u) {
    union { unsigned int i; float f; } v; v.i = ((unsigned int)u) << 16; return v.f;
}
__device__ inline bf16_t f2bf(float f) {
    union { float f; unsigned int i; } v; v.f = f;
    unsigned int x = v.i;
    return (bf16_t)((x + 0x7fffu + ((x >> 16) & 1u)) >> 16);  // RNE
}
// tanh(x) = 1 - 2/(exp(2x)+1)  — stable at both infinities, ~1e-6 abs error
__device__ inline float fast_tanh(float x) {
    float e = __expf(2.f * x);
    return 1.f - __fdividef(2.f, e + 1.f);
}

// pin a float4 in VGPRs (compiler cannot rematerialize past this)
#define OPQ(v) asm volatile("" : "+v"(v.x), "+v"(v.y), "+v"(v.z), "+v"(v.w))

#define W16LOAD \
    float4 w0=wr[0],w1=wr[1],w2=wr[2],w3=wr[3],w4=wr[4],w5=wr[5],w6=wr[6],w7=wr[7], \
           w8=wr[8],w9=wr[9],w10=wr[10],w11=wr[11],w12=wr[12],w13=wr[13],w14=wr[14],w15=wr[15];
#define W16PIN \
    OPQ(w0);OPQ(w1);OPQ(w2);OPQ(w3);OPQ(w4);OPQ(w5);OPQ(w6);OPQ(w7); \
    OPQ(w8);OPQ(w9);OPQ(w10);OPQ(w11);OPQ(w12);OPQ(w13);OPQ(w14);OPQ(w15);
#define W32LOAD W16LOAD \
    float4 w16=wr[16],w17=wr[17],w18=wr[18],w19=wr[19],w20=wr[20],w21=wr[21],w22=wr[22],w23=wr[23], \
           w24=wr[24],w25=wr[25],w26=wr[26],w27=wr[27],w28=wr[28],w29=wr[29],w30=wr[30],w31=wr[31];
#define W32PIN W16PIN \
    OPQ(w16);OPQ(w17);OPQ(w18);OPQ(w19);OPQ(w20);OPQ(w21);OPQ(w22);OPQ(w23); \
    OPQ(w24);OPQ(w25);OPQ(w26);OPQ(w27);OPQ(w28);OPQ(w29);OPQ(w30);OPQ(w31);
#define ACC4(n) { float4 hv = hp[n]; \
    a0 = fmaf(hv.x, w##n.x, a0); a1 = fmaf(hv.y, w##n.y, a1); \
    a2 = fmaf(hv.z, w##n.z, a2); a3 = fmaf(hv.w, w##n.w, a3); }
#define ACC16 ACC4(0)ACC4(1)ACC4(2)ACC4(3)ACC4(4)ACC4(5)ACC4(6)ACC4(7) \
              ACC4(8)ACC4(9)ACC4(10)ACC4(11)ACC4(12)ACC4(13)ACC4(14)ACC4(15)
#define ACC32 ACC16 \
              ACC4(16)ACC4(17)ACC4(18)ACC4(19)ACC4(20)ACC4(21)ACC4(22)ACC4(23) \
              ACC4(24)ACC4(25)ACC4(26)ACC4(27)ACC4(28)ACC4(29)ACC4(30)ACC4(31)

// ---------------- kernel 1: embedding gather + layer-1 input GEMM (+both biases)
__global__ __launch_bounds__(128)
__attribute__((amdgpu_waves_per_eu(1, 4)))
void k_embed_pre1(
    const int* __restrict__ x, const float* __restrict__ emb,
    const float* __restrict__ Wih1, const float* __restrict__ bih1,
    const float* __restrict__ bhh1, float* __restrict__ pre1)
{
    __shared__ __align__(16) float se[8 * EMB];
    __shared__ int stok[8];
    const int base = blockIdx.x * 8;
    const int i = threadIdx.x;
    if (i < 8) stok[i] = x[base + i];
    __syncthreads();
    {   // gather 8 emb rows (16 float4 each) — one float4 per thread
        int p = i >> 4, c = i & 15;
        ((float4*)se)[i] = ((const float4*)(emb + (size_t)stok[p] * EMB))[c];
    }
    __syncthreads();
    const float4* wr = reinterpret_cast<const float4*>(Wih1 + i * EMB);
    W16LOAD; W16PIN;
    const float bias = bih1[i] + bhh1[i];
    float* outp = pre1 + (size_t)base * HID + i;
#pragma unroll
    for (int p = 0; p < 8; ++p) {
        const float4* hp = reinterpret_cast<const float4*>(se + p * EMB);
        float a0 = 0, a1 = 0, a2 = 0, a3 = 0;
        ACC16;
        outp[p * HID] = bias + ((a0 + a1) + (a2 + a3));
    }
}

// ---------------- kernel 2: layer-1 recurrence. one block per batch row,
// 256 threads, 2-way K-split, 64 pinned weight floats/thread (VGPR=132, R6).
// CH-step LDS staging of pre/out: barriers drain vmcnt(0) (R6 finding), so
// global traffic is batched once per CH steps instead of every step.
__global__ __launch_bounds__(256)
__attribute__((amdgpu_waves_per_eu(1, 1)))
void k_rnn1(
    const float* __restrict__ pre1, const float* __restrict__ Whh1,
    bf16_t* __restrict__ out1)
{
    __shared__ __align__(16) float hb[2][HID];     // double-buffered hidden state
    __shared__ __align__(16) float sp[2][HID];     // K-split partial sums
    __shared__ __align__(16) float spre[CH * HID]; // staged pre rows (16 KB)
    __shared__ __align__(16) bf16_t sout[CH * HID];// staged out rows (8 KB)
    const int b    = blockIdx.x;
    const int tid  = threadIdx.x;
    const int i    = tid & 127;
    const int half = tid >> 7;
    const float4* wr = reinterpret_cast<const float4*>(Whh1 + i * HID + half * 64);
    W16LOAD; W16PIN;
    if (tid < 128) hb[0][i] = 0.f;
    const float4* gsrc = reinterpret_cast<const float4*>(pre1 + (size_t)b * 512 * HID);
    uint4*        gdst = reinterpret_cast<uint4*>(out1 + (size_t)b * 512 * HID);
    float4*       spv  = reinterpret_cast<float4*>(spre);
    const uint4*  sov  = reinterpret_cast<const uint4*>(sout);
    for (int c = 0; c < 512 / CH; ++c) {
        // stage next CH pre rows: CH*HID/4 float4 = 1024, 4 per thread
        float4 r0 = gsrc[c * 1024 + tid];
        float4 r1 = gsrc[c * 1024 + tid + 256];
        float4 r2 = gsrc[c * 1024 + tid + 512];
        float4 r3 = gsrc[c * 1024 + tid + 768];
        // flush previous chunk's outputs (LDS stable since last barrier)
        if (c) {
            uint4 f0 = sov[tid], f1 = sov[tid + 256];
            gdst[(c - 1) * 512 + tid]       = f0;
            gdst[(c - 1) * 512 + tid + 256] = f1;
        }
        spv[tid]       = r0;
        spv[tid + 256] = r1;
        spv[tid + 512] = r2;
        spv[tid + 768] = r3;
        __syncthreads();
        for (int s = 0; s < CH; ++s) {
            const int t = c * CH + s;
            const float4* hp = reinterpret_cast<const float4*>(hb[t & 1] + half * 64);
            float a0 = 0, a1 = 0, a2 = 0, a3 = 0;
            ACC16;
            sp[half][i] = (a0 + a1) + (a2 + a3);
            __syncthreads();
            if (tid < 128) {   // wave-uniform (waves 0,1)
                float hn = fast_tanh(spre[s * HID + i] + sp[0][i] + sp[1][i]);
                hb[(t + 1) & 1][i] = hn;
                sout[s * HID + i] = f2bf(hn);
            }
            __syncthreads();
        }
    }
    // final chunk flush
    uint4 f0 = sov[tid], f1 = sov[tid + 256];
    gdst[15 * 512 + tid]       = f0;
    gdst[15 * 512 + tid + 256] = f1;
}

// ---------------- kernel 3: layer-2 input GEMM (+both biases), 16 positions/block
__global__ __launch_bounds__(128)
__attribute__((amdgpu_waves_per_eu(1, 2)))
void k_pre2(
    const bf16_t* __restrict__ out1, const float* __restrict__ Wih2,
    const float* __restrict__ bih2, const float* __restrict__ bhh2,
    float* __restrict__ pre2)
{
    __shared__ __align__(16) float se[16 * HID];
    const int base = blockIdx.x * 16;
    const int i = threadIdx.x;
    const uint4* src = reinterpret_cast<const uint4*>(out1 + (size_t)base * HID);
#pragma unroll
    for (int k = 0; k < 2; ++k) {
        int idx = i + k * 128;
        uint4 u = src[idx];
        int e = idx * 8;
        se[e+0] = bf2f((bf16_t)(u.x & 0xffff)); se[e+1] = bf2f((bf16_t)(u.x >> 16));
        se[e+2] = bf2f((bf16_t)(u.y & 0xffff)); se[e+3] = bf2f((bf16_t)(u.y >> 16));
        se[e+4] = bf2f((bf16_t)(u.z & 0xffff)); se[e+5] = bf2f((bf16_t)(u.z >> 16));
        se[e+6] = bf2f((bf16_t)(u.w & 0xffff)); se[e+7] = bf2f((bf16_t)(u.w >> 16));
    }
    __syncthreads();
    const float4* wr = reinterpret_cast<const float4*>(Wih2 + i * HID);
    W32LOAD; W32PIN;
    const float bias = bih2[i] + bhh2[i];
    float* outp = pre2 + (size_t)base * HID + i;
#pragma unroll
    for (int p = 0; p < 16; ++p) {
        const float4* hp = reinterpret_cast<const float4*>(se + p * HID);
        float a0 = 0, a1 = 0, a2 = 0, a3 = 0;
        ACC32;
        outp[p * HID] = bias + ((a0 + a1) + (a2 + a3));
    }
}

// block-wide sum over the 128 values held by tid<128 (all 256 threads call;
// half-1 threads must pass v=0). Unconditional barriers.
__device__ inline float bsum_all(float v, volatile float* sc, int tid) {
#pragma unroll
    for (int off = 32; off > 0; off >>= 1) v += __shfl_down(v, off, 64);
    __syncthreads();
    if (tid < 128 && (tid & 63) == 0) sc[tid >> 6] = v;
    __syncthreads();
    return sc[0] + sc[1];
}

// ---------------- kernel 4: layer-2 recurrence + LN -> proj+tanh -> LN epilogue
__global__ __launch_bounds__(256)
__attribute__((amdgpu_waves_per_eu(1, 1)))
void k_rnn2_out(
    const float* __restrict__ pre2, const float* __restrict__ Whh2,
    const float* __restrict__ ln_g, const float* __restrict__ ln_b,
    const float* __restrict__ projW, const float* __restrict__ proj_b,
    const float* __restrict__ on_g, const float* __restrict__ on_b,
    float* __restrict__ out)
{
    __shared__ __align__(16) float hb[2][HID];
    __shared__ __align__(16) float sp[2][HID];
    __shared__ __align__(16) float spre[CH * HID];
    __shared__ float sc[2];
    const int b    = blockIdx.x;
    const int tid  = threadIdx.x;
    const int i    = tid & 127;
    const int half = tid >> 7;
    const float4* wr = reinterpret_cast<const float4*>(Whh2 + i * HID + half * 64);
    W16LOAD; W16PIN;
    if (tid < 128) hb[0][i] = 0.f;
    const float4* gsrc = reinterpret_cast<const float4*>(pre2 + (size_t)b * 512 * HID);
    float4*       spv  = reinterpret_cast<float4*>(spre);
    float hn = 0.f;                 // final h, valid for tid<128
    for (int c = 0; c < 512 / CH; ++c) {
        float4 r0 = gsrc[c * 1024 + tid];
        float4 r1 = gsrc[c * 1024 + tid + 256];
        float4 r2 = gsrc[c * 1024 + tid + 512];
        float4 r3 = gsrc[c * 1024 + tid + 768];
        spv[tid]       = r0;
        spv[tid + 256] = r1;
        spv[tid + 512] = r2;
        spv[tid + 768] = r3;
        __syncthreads();
        for (int s = 0; s < CH; ++s) {
            const int t = c * CH + s;
            const float4* hp = reinterpret_cast<const float4*>(hb[t & 1] + half * 64);
            float a0 = 0, a1 = 0, a2 = 0, a3 = 0;
            ACC16;
            sp[half][i] = (a0 + a1) + (a2 + a3);
            __syncthreads();
            if (tid < 128) {
                hn = fast_tanh(spre[s * HID + i] + sp[0][i] + sp[1][i]);
                hb[(t + 1) & 1][i] = hn;
            }
            __syncthreads();
        }
    }
    // ---- layernorm 1 (values valid for tid<128; barriers executed by all)
    float s1 = bsum_all(tid < 128 ? hn : 0.f, sc, tid);
    float s2 = bsum_all(tid < 128 ? hn * hn : 0.f, sc, tid);
    float mu = s1 * (1.f / 128.f);
    float var = s2 * (1.f / 128.f) - mu * mu;
    __syncthreads();
    if (tid < 128) hb[0][i] = (hn - mu) * rsqrtf(var + 1e-5f) * ln_g[i] + ln_b[i];
    __syncthreads();
    // ---- proj + tanh (one-time; first 128 threads)
    float pv = 0.f;
    if (tid < 128) {
        float a0 = proj_b[i], a1 = 0, a2 = 0, a3 = 0;
        const float4* hp = reinterpret_cast<const float4*>(hb[0]);
        const float4* pr = reinterpret_cast<const float4*>(projW + i * HID);
#pragma unroll
        for (int c = 0; c < HID / 4; ++c) {
            float4 u = pr[c];
            float4 hv = hp[c];
            a0 = fmaf(hv.x, u.x, a0); a1 = fmaf(hv.y, u.y, a1);
            a2 = fmaf(hv.z, u.z, a2); a3 = fmaf(hv.w, u.w, a3);
        }
        pv = tanhf((a0 + a1) + (a2 + a3));
    }
    // ---- layernorm 2
    float t1 = bsum_all(pv, sc, tid);
    float t2 = bsum_all(pv * pv, sc, tid);
    float mu2 = t1 * (1.f / 128.f);
    float var2 = t2 * (1.f / 128.f) - mu2 * mu2;
    if (tid < 128)
        out[(size_t)b * HID + i] = (pv - mu2) * rsqrtf(var2 + 1e-5f) * on_g[i] + on_b[i];
}

extern "C" void kernel_launch(void* const* d_in, const int* in_sizes, int n_in,
                              void* d_out, int out_size, void* d_ws, size_t ws_size,
                              hipStream_t stream)
{
    const int*   x     = (const int*)  d_in[0];
    const float* emb   = (const float*)d_in[1];
    const float* Wih1  = (const float*)d_in[2];
    const float* bih1  = (const float*)d_in[3];
    const float* Whh1  = (const float*)d_in[4];
    const float* bhh1  = (const float*)d_in[5];
    const float* Wih2  = (const float*)d_in[6];
    const float* bih2  = (const float*)d_in[7];
    const float* Whh2  = (const float*)d_in[8];
    const float* bhh2  = (const float*)d_in[9];
    const float* ln_g  = (const float*)d_in[10];
    const float* ln_b  = (const float*)d_in[11];
    const float* projW = (const float*)d_in[12];
    const float* projb = (const float*)d_in[13];
    const float* on_g  = (const float*)d_in[14];
    const float* on_b  = (const float*)d_in[15];

    char* ws = (char*)d_ws;
    float*  pre  = (float*)ws;                               // 64 MiB fp32, reused by both layers
    bf16_t* out1 = (bf16_t*)(ws + (size_t)BT * HID * 4);     // 32 MiB bf16

    k_embed_pre1<<<BT / 8, 128, 0, stream>>>(x, emb, Wih1, bih1, bhh1, pre);
    k_rnn1<<<256, 256, 0, stream>>>(pre, Whh1, out1);
    k_pre2<<<BT / 16, 128, 0, stream>>>(out1, Wih2, bih2, bhh2, pre);
    k_rnn2_out<<<256, 256, 0, stream>>>(pre, Whh2, ln_g, ln_b, projW, projb,
                                        on_g, on_b, (float*)d_out);
}